// Round 7
// baseline (3085.368 us; speedup 1.0000x reference)
//
#include <hip/hip_runtime.h>
#include <hip/hip_bf16.h>

#define N_MOL 128
#define STRESS_FLOATS (N_MOL * 9)   // 1152
#define NXCD 8
#define EDGE_BLOCKS 2048
#define BLK 256

// ---------------------------------------------------------------------------
// Physical XCD id of the executing wave (dispatch->XCD mapping is undefined,
// so this MUST come from hardware, not blockIdx).
// ---------------------------------------------------------------------------
__device__ __forceinline__ int xcc_id() {
    int x;
    asm volatile("s_getreg_b32 %0, hwreg(HW_REG_XCC_ID)" : "=s"(x));
    return x & (NXCD - 1);
}

// Workgroup-scope relaxed f32 add: emits global_atomic_add_f32 WITHOUT the
// sc1 (agent-coherent) bit -> RMW executes at the local XCD's L2 instead of
// the device-coherent memory-side path (the ~700 GB/s wall measured in r4/r6).
// Atomicity across all CUs of one XCD is provided by the TCC RMW unit;
// cross-XCD isolation comes from per-XCD replicas.
__device__ __forceinline__ void l2_atomic_add(float* p, float v) {
    __hip_atomic_fetch_add(p, v, __ATOMIC_RELAXED, __HIP_MEMORY_SCOPE_WORKGROUP);
}

// ---------------------------------------------------------------------------
__global__ void zero_f32_kernel(float4* __restrict__ p, int n4) {
    int i = blockIdx.x * blockDim.x + threadIdx.x;
    if (i < n4) p[i] = make_float4(0.f, 0.f, 0.f, 0.f);
}

// ---------------------------------------------------------------------------
// Edge kernel (replica path):
//  forces: 6 f32 atomics into this XCD's replica, executed at local L2
//  stress: LDS accumulate -> non-atomic per-block partial [EDGE_BLOCKS][1152]
// ---------------------------------------------------------------------------
__global__ void __launch_bounds__(256)
edge_kernel_xcd(const float* __restrict__ dEdRij,
                const float* __restrict__ Rij,
                const int*   __restrict__ idx_i,
                const int*   __restrict__ idx_j,
                const int*   __restrict__ idx_m,
                float* __restrict__ frep,     // [NXCD][N][3]
                float* __restrict__ spart,    // [EDGE_BLOCKS][1152]
                int E, int N)
{
    __shared__ float smem[STRESS_FLOATS];
    for (int t = threadIdx.x; t < STRESS_FLOATS; t += blockDim.x)
        smem[t] = 0.f;
    __syncthreads();

    float* facc = frep + (size_t)xcc_id() * (size_t)N * 3;

    const int stride = gridDim.x * blockDim.x;
    for (int e = blockIdx.x * blockDim.x + threadIdx.x; e < E; e += stride) {
        const int i = idx_i[e];
        const int j = idx_j[e];

        const float dx = dEdRij[3 * e + 0];
        const float dy = dEdRij[3 * e + 1];
        const float dz = dEdRij[3 * e + 2];
        const float rx = Rij[3 * e + 0];
        const float ry = Rij[3 * e + 1];
        const float rz = Rij[3 * e + 2];

        // forces into local-L2 replica
        float* fi = facc + 3 * (size_t)i;
        l2_atomic_add(fi + 0,  dx);
        l2_atomic_add(fi + 1,  dy);
        l2_atomic_add(fi + 2,  dz);
        float* fj = facc + 3 * (size_t)j;
        l2_atomic_add(fj + 0, -dx);
        l2_atomic_add(fj + 1, -dy);
        l2_atomic_add(fj + 2, -dz);

        // stress per-molecule in LDS (ds_add_f32 — measured cheap, 0 conflicts)
        const int m = idx_m[i];
        float* s = &smem[m * 9];
        atomicAdd(&s[0], rx * dx);
        atomicAdd(&s[1], rx * dy);
        atomicAdd(&s[2], rx * dz);
        atomicAdd(&s[3], ry * dx);
        atomicAdd(&s[4], ry * dy);
        atomicAdd(&s[5], ry * dz);
        atomicAdd(&s[6], rz * dx);
        atomicAdd(&s[7], rz * dy);
        atomicAdd(&s[8], rz * dz);
    }

    __syncthreads();
    float* sp = spart + (size_t)blockIdx.x * STRESS_FLOATS;
    for (int t = threadIdx.x; t < STRESS_FLOATS; t += blockDim.x)
        sp[t] = smem[t];
}

// ---------------------------------------------------------------------------
// forces: sum 8 replicas -> d_out [N*3] (full overwrite)
// ---------------------------------------------------------------------------
__global__ void reduce_forces_kernel(const float* __restrict__ frep,
                                     float* __restrict__ forces, int n3)
{
    int t = blockIdx.x * blockDim.x + threadIdx.x;
    if (t >= n3) return;
    float a = 0.f;
    #pragma unroll
    for (int r = 0; r < NXCD; ++r)
        a += frep[(size_t)r * n3 + t];
    forces[t] = a;
}

// ---------------------------------------------------------------------------
// stress partials [EDGE_BLOCKS][1152] -> d_out [1152], divided by cell volume
// ---------------------------------------------------------------------------
__global__ void reduce_stress_kernel(const float* __restrict__ spart,
                                     const float* __restrict__ cell,
                                     float* __restrict__ out_stress,
                                     int nblocks)
{
    int t = blockIdx.x * blockDim.x + threadIdx.x;
    if (t >= STRESS_FLOATS) return;
    float acc = 0.f;
    #pragma unroll 8
    for (int b = 0; b < nblocks; ++b)
        acc += spart[(size_t)b * STRESS_FLOATS + t];
    const int m = t / 9;
    const float* c = &cell[m * 9];
    const float a0 = c[0], a1 = c[1], a2 = c[2];
    const float b0 = c[3], b1 = c[4], b2 = c[5];
    const float c0 = c[6], c1 = c[7], c2 = c[8];
    const float x0 = b1 * c2 - b2 * c1;
    const float x1 = b2 * c0 - b0 * c2;
    const float x2 = b0 * c1 - b1 * c0;
    const float vol = a0 * x0 + a1 * x1 + a2 * x2;
    out_stress[t] = acc / vol;
}

// ===========================================================================
// Fallback (ws too small): round-6 measured f64 path
// ===========================================================================
__global__ void zero_f64_kernel(double* __restrict__ p, int n) {
    int i = blockIdx.x * blockDim.x + threadIdx.x;
    if (i < n) p[i] = 0.0;
}

__global__ void __launch_bounds__(256)
edge_kernel_f64(const float* __restrict__ dEdRij,
                const float* __restrict__ Rij,
                const int*   __restrict__ idx_i,
                const int*   __restrict__ idx_j,
                const int*   __restrict__ idx_m,
                double* __restrict__ facc,
                float*  __restrict__ spart,
                int E)
{
    __shared__ float smem[STRESS_FLOATS];
    for (int t = threadIdx.x; t < STRESS_FLOATS; t += blockDim.x) smem[t] = 0.f;
    __syncthreads();
    const int stride = gridDim.x * blockDim.x;
    for (int e = blockIdx.x * blockDim.x + threadIdx.x; e < E; e += stride) {
        const int i = idx_i[e], j = idx_j[e];
        const float dx = dEdRij[3*e+0], dy = dEdRij[3*e+1], dz = dEdRij[3*e+2];
        const float rx = Rij[3*e+0],    ry = Rij[3*e+1],    rz = Rij[3*e+2];
        double* fi = facc + 3 * (size_t)i;
        unsafeAtomicAdd(fi + 0, (double) dx);
        unsafeAtomicAdd(fi + 1, (double) dy);
        unsafeAtomicAdd(fi + 2, (double) dz);
        double* fj = facc + 3 * (size_t)j;
        unsafeAtomicAdd(fj + 0, (double)-dx);
        unsafeAtomicAdd(fj + 1, (double)-dy);
        unsafeAtomicAdd(fj + 2, (double)-dz);
        const int m = idx_m[i];
        float* s = &smem[m * 9];
        atomicAdd(&s[0], rx*dx); atomicAdd(&s[1], rx*dy); atomicAdd(&s[2], rx*dz);
        atomicAdd(&s[3], ry*dx); atomicAdd(&s[4], ry*dy); atomicAdd(&s[5], ry*dz);
        atomicAdd(&s[6], rz*dx); atomicAdd(&s[7], rz*dy); atomicAdd(&s[8], rz*dz);
    }
    __syncthreads();
    float* sp = spart + (size_t)blockIdx.x * STRESS_FLOATS;
    for (int t = threadIdx.x; t < STRESS_FLOATS; t += blockDim.x) sp[t] = smem[t];
}

__global__ void reduce_forces_f64_kernel(const double* __restrict__ facc,
                                         float* __restrict__ forces, int n3)
{
    int t = blockIdx.x * blockDim.x + threadIdx.x;
    if (t < n3) forces[t] = (float)facc[t];
}

// ===========================================================================
extern "C" void kernel_launch(void* const* d_in, const int* in_sizes, int n_in,
                              void* d_out, int out_size, void* d_ws, size_t ws_size,
                              hipStream_t stream)
{
    const float* dEdRij = (const float*)d_in[0];
    const float* Rij    = (const float*)d_in[1];
    const float* R      = (const float*)d_in[2];  (void)R;
    const float* cell   = (const float*)d_in[3];
    const int*   idx_i  = (const int*)d_in[4];
    const int*   idx_j  = (const int*)d_in[5];
    const int*   idx_m  = (const int*)d_in[6];

    const int E = in_sizes[0] / 3;   // 10,000,000
    const int N = in_sizes[2] / 3;   // 200,000
    const int n3 = N * 3;

    float* out        = (float*)d_out;
    float* forces     = out;
    float* stress_out = out + (size_t)n3;

    const size_t frep_floats  = (size_t)NXCD * n3;                    // 4.8M
    const size_t spart_floats = (size_t)EDGE_BLOCKS * STRESS_FLOATS;  // 2.36M
    const size_t need_bytes   = (frep_floats + spart_floats) * sizeof(float);

    const size_t f64_need = (size_t)n3 * sizeof(double)
                          + spart_floats * sizeof(float);

    if (ws_size >= need_bytes) {
        float* frep  = (float*)d_ws;
        float* spart = frep + frep_floats;

        const int n4 = (int)(frep_floats / 4);   // divisible: 4.8M/4
        zero_f32_kernel<<<(n4 + BLK - 1) / BLK, BLK, 0, stream>>>(
            (float4*)frep, n4);

        edge_kernel_xcd<<<EDGE_BLOCKS, BLK, 0, stream>>>(
            dEdRij, Rij, idx_i, idx_j, idx_m, frep, spart, E, N);

        reduce_forces_kernel<<<(n3 + BLK - 1) / BLK, BLK, 0, stream>>>(
            frep, forces, n3);

        reduce_stress_kernel<<<(STRESS_FLOATS + BLK - 1) / BLK, BLK, 0, stream>>>(
            spart, cell, stress_out, EDGE_BLOCKS);
    } else if (ws_size >= f64_need) {
        double* facc  = (double*)d_ws;
        float*  spart = (float*)(facc + n3);

        zero_f64_kernel<<<(n3 + BLK - 1) / BLK, BLK, 0, stream>>>(facc, n3);
        edge_kernel_f64<<<EDGE_BLOCKS, BLK, 0, stream>>>(
            dEdRij, Rij, idx_i, idx_j, idx_m, facc, spart, E);
        reduce_forces_f64_kernel<<<(n3 + BLK - 1) / BLK, BLK, 0, stream>>>(
            facc, forces, n3);
        reduce_stress_kernel<<<(STRESS_FLOATS + BLK - 1) / BLK, BLK, 0, stream>>>(
            spart, cell, stress_out, EDGE_BLOCKS);
    }
}

// Round 9
// 1715.066 us; speedup vs baseline: 1.7990x; 1.7990x over previous
//
#include <hip/hip_runtime.h>
#include <hip/hip_bf16.h>

#define N_MOL 128
#define STRESS_FLOATS (N_MOL * 9)   // 1152
#define APB 400                     // atoms per bucket
#define MAXB 512                    // LDS sizing bound for bucket arrays
#define EPB 4096                    // edges per scatter block
#define BLK 256

// ---------------------------------------------------------------------------
__global__ void zero_f32_kernel(float* __restrict__ p, int n) {
    int i = blockIdx.x * blockDim.x + threadIdx.x;
    if (i < n) p[i] = 0.f;
}

// ---------------------------------------------------------------------------
// Pass C: per-block histogram -> slot reservation -> record scatter + stress.
// Records: float4(atom_id_bits, fx, fy, fz). Only global atomics left are the
// per-(block,bucket) reservations (~500/block).
// ---------------------------------------------------------------------------
__global__ void __launch_bounds__(256)
scatter_kernel(const float* __restrict__ dEdRij,
               const float* __restrict__ Rij,
               const int*   __restrict__ idx_i,
               const int*   __restrict__ idx_j,
               const int*   __restrict__ idx_m,
               float4* __restrict__ rec,    // [B][CAP]
               int*    __restrict__ cnt,    // [B], zeroed per chunk
               float*  __restrict__ spart,  // stress partials, row per block
               int e0_chunk, int n_edges_chunk, int B, int CAP, int spart_row0)
{
    __shared__ int   hist[MAXB];
    __shared__ int   base[MAXB];
    __shared__ float smem[STRESS_FLOATS];

    for (int t = threadIdx.x; t < MAXB; t += blockDim.x) hist[t] = 0;
    for (int t = threadIdx.x; t < STRESS_FLOATS; t += blockDim.x) smem[t] = 0.f;
    __syncthreads();

    const int be0 = e0_chunk + blockIdx.x * EPB;
    const int be1 = min(be0 + EPB, e0_chunk + n_edges_chunk);

    // phase 1: bucket histogram (idx-only reads; floats read in phase 2)
    for (int e = be0 + threadIdx.x; e < be1; e += blockDim.x) {
        atomicAdd(&hist[idx_i[e] / APB], 1);
        atomicAdd(&hist[idx_j[e] / APB], 1);
    }
    __syncthreads();

    // reservation: one global atomic per non-empty (block,bucket)
    for (int t = threadIdx.x; t < B; t += blockDim.x) {
        int h = hist[t];
        base[t] = h ? atomicAdd(&cnt[t], h) : 0;
        hist[t] = 0;                       // reuse as local cursor
    }
    __syncthreads();

    // phase 2: write records + stress LDS accumulation
    for (int e = be0 + threadIdx.x; e < be1; e += blockDim.x) {
        const int i = idx_i[e];
        const int j = idx_j[e];
        const float dx = dEdRij[3*e+0], dy = dEdRij[3*e+1], dz = dEdRij[3*e+2];
        const float rx = Rij[3*e+0],    ry = Rij[3*e+1],    rz = Rij[3*e+2];

        // stress: outer(Rij, dEdRij) per molecule (ds_add_f32, measured free)
        const int m = idx_m[i];
        float* s = &smem[m * 9];
        atomicAdd(&s[0], rx * dx);
        atomicAdd(&s[1], rx * dy);
        atomicAdd(&s[2], rx * dz);
        atomicAdd(&s[3], ry * dx);
        atomicAdd(&s[4], ry * dy);
        atomicAdd(&s[5], ry * dz);
        atomicAdd(&s[6], rz * dx);
        atomicAdd(&s[7], rz * dy);
        atomicAdd(&s[8], rz * dz);

        // i-record
        int bi = i / APB;
        int pos = atomicAdd(&hist[bi], 1);          // LDS cursor
        int slot = base[bi] + pos;
        if (slot < CAP)
            rec[(size_t)bi * CAP + slot] =
                make_float4(__int_as_float(i), dx, dy, dz);

        // j-record (negated)
        int bj = j / APB;
        pos  = atomicAdd(&hist[bj], 1);
        slot = base[bj] + pos;
        if (slot < CAP)
            rec[(size_t)bj * CAP + slot] =
                make_float4(__int_as_float(j), -dx, -dy, -dz);
    }

    __syncthreads();
    float* sp = spart + (size_t)(spart_row0 + blockIdx.x) * STRESS_FLOATS;
    for (int t = threadIdx.x; t < STRESS_FLOATS; t += blockDim.x)
        sp[t] = smem[t];
}

// ---------------------------------------------------------------------------
// Pass D: one block per bucket. Coalesced record read -> LDS accumulate ->
// non-atomic add into forces (exclusive atom ownership per block).
// ---------------------------------------------------------------------------
__global__ void __launch_bounds__(256)
accum_kernel(const float4* __restrict__ rec,
             const int*    __restrict__ cnt,
             float* __restrict__ forces,
             int CAP, int n3)
{
    __shared__ float facc[APB * 3];
    const int b = blockIdx.x;
    for (int t = threadIdx.x; t < APB * 3; t += blockDim.x) facc[t] = 0.f;
    __syncthreads();

    int n = cnt[b];
    if (n > CAP) n = CAP;
    const float4* rb = rec + (size_t)b * CAP;

    for (int r = threadIdx.x; r < n; r += blockDim.x) {
        float4 q = rb[r];
        int a = __float_as_int(q.x);
        int l = a - b * APB;
        atomicAdd(&facc[l * 3 + 0], q.y);
        atomicAdd(&facc[l * 3 + 1], q.z);
        atomicAdd(&facc[l * 3 + 2], q.w);
    }
    __syncthreads();

    const int o = b * APB * 3;
    for (int t = threadIdx.x; t < APB * 3; t += blockDim.x) {
        int a3 = o + t;
        if (a3 < n3) forces[a3] += facc[t];
    }
}

// ---------------------------------------------------------------------------
// stress partials [rows][1152] -> d_out [1152], divided by cell volume
// ---------------------------------------------------------------------------
__global__ void reduce_stress_kernel(const float* __restrict__ spart,
                                     const float* __restrict__ cell,
                                     float* __restrict__ out_stress,
                                     int rows)
{
    int t = blockIdx.x * blockDim.x + threadIdx.x;
    if (t >= STRESS_FLOATS) return;
    float acc = 0.f;
    for (int b = 0; b < rows; ++b)
        acc += spart[(size_t)b * STRESS_FLOATS + t];
    const int m = t / 9;
    const float* c = &cell[m * 9];
    const float a0 = c[0], a1 = c[1], a2 = c[2];
    const float b0 = c[3], b1 = c[4], b2 = c[5];
    const float c0 = c[6], c1 = c[7], c2 = c[8];
    const float x0 = b1 * c2 - b2 * c1;
    const float x1 = b2 * c0 - b0 * c2;
    const float x2 = b0 * c1 - b1 * c0;
    const float vol = a0 * x0 + a1 * x1 + a2 * x2;
    out_stress[t] = acc / vol;
}

// ===========================================================================
// Fallback: round-6 measured f64 atomic path (2595 us, known passing)
// ===========================================================================
__global__ void zero_f64_kernel(double* __restrict__ p, int n) {
    int i = blockIdx.x * blockDim.x + threadIdx.x;
    if (i < n) p[i] = 0.0;
}

__global__ void __launch_bounds__(256)
edge_kernel_f64(const float* __restrict__ dEdRij,
                const float* __restrict__ Rij,
                const int*   __restrict__ idx_i,
                const int*   __restrict__ idx_j,
                const int*   __restrict__ idx_m,
                double* __restrict__ facc,
                float*  __restrict__ spart,
                int E)
{
    __shared__ float smem[STRESS_FLOATS];
    for (int t = threadIdx.x; t < STRESS_FLOATS; t += blockDim.x) smem[t] = 0.f;
    __syncthreads();
    const int stride = gridDim.x * blockDim.x;
    for (int e = blockIdx.x * blockDim.x + threadIdx.x; e < E; e += stride) {
        const int i = idx_i[e], j = idx_j[e];
        const float dx = dEdRij[3*e+0], dy = dEdRij[3*e+1], dz = dEdRij[3*e+2];
        const float rx = Rij[3*e+0],    ry = Rij[3*e+1],    rz = Rij[3*e+2];
        double* fi = facc + 3 * (size_t)i;
        unsafeAtomicAdd(fi + 0, (double) dx);
        unsafeAtomicAdd(fi + 1, (double) dy);
        unsafeAtomicAdd(fi + 2, (double) dz);
        double* fj = facc + 3 * (size_t)j;
        unsafeAtomicAdd(fj + 0, (double)-dx);
        unsafeAtomicAdd(fj + 1, (double)-dy);
        unsafeAtomicAdd(fj + 2, (double)-dz);
        const int m = idx_m[i];
        float* s = &smem[m * 9];
        atomicAdd(&s[0], rx*dx); atomicAdd(&s[1], rx*dy); atomicAdd(&s[2], rx*dz);
        atomicAdd(&s[3], ry*dx); atomicAdd(&s[4], ry*dy); atomicAdd(&s[5], ry*dz);
        atomicAdd(&s[6], rz*dx); atomicAdd(&s[7], rz*dy); atomicAdd(&s[8], rz*dz);
    }
    __syncthreads();
    float* sp = spart + (size_t)blockIdx.x * STRESS_FLOATS;
    for (int t = threadIdx.x; t < STRESS_FLOATS; t += blockDim.x) sp[t] = smem[t];
}

__global__ void reduce_forces_f64_kernel(const double* __restrict__ facc,
                                         float* __restrict__ forces, int n3)
{
    int t = blockIdx.x * blockDim.x + threadIdx.x;
    if (t < n3) forces[t] = (float)facc[t];
}

// ===========================================================================
extern "C" void kernel_launch(void* const* d_in, const int* in_sizes, int n_in,
                              void* d_out, int out_size, void* d_ws, size_t ws_size,
                              hipStream_t stream)
{
    const float* dEdRij = (const float*)d_in[0];
    const float* Rij    = (const float*)d_in[1];
    const float* R      = (const float*)d_in[2];  (void)R;
    const float* cell   = (const float*)d_in[3];
    const int*   idx_i  = (const int*)d_in[4];
    const int*   idx_j  = (const int*)d_in[5];
    const int*   idx_m  = (const int*)d_in[6];

    const int E  = in_sizes[0] / 3;   // 10,000,000
    const int N  = in_sizes[2] / 3;   // 200,000
    const int n3 = N * 3;

    float* out        = (float*)d_out;
    float* forces     = out;
    float* stress_out = out + (size_t)n3;

    const int B = (N + APB - 1) / APB;   // 500

    // ---- choose chunk count so ws fits: rec[B][CAP] + spart[rows][1152] + cnt[B]
    int  nchunks = 0, CAP = 0, total_rows = 0;
    size_t rec_f4 = 0, spart_f = 0;
    if (B <= MAXB) {
        const int cand[4] = {5, 10, 20, 40};
        for (int ci = 0; ci < 4; ++ci) {
            int nc = cand[ci];
            int CH = (E + nc - 1) / nc;
            int cap = (3 * CH) / B + 64;              // 1.5x headroom
            int rows = 0;
            for (int s = 0; s < E; s += CH) {
                int ce = min(CH, E - s);
                rows += (ce + EPB - 1) / EPB;
            }
            size_t need = (size_t)B * cap * sizeof(float4)
                        + (size_t)rows * STRESS_FLOATS * sizeof(float)
                        + (size_t)B * sizeof(int) + 256;
            if (need <= ws_size) {
                nchunks = nc; CAP = cap; total_rows = rows;
                rec_f4  = (size_t)B * cap;
                spart_f = (size_t)rows * STRESS_FLOATS;
                break;
            }
        }
    }

    if (nchunks > 0) {
        float4* rec   = (float4*)d_ws;
        float*  spart = (float*)(rec + rec_f4);
        int*    cnt   = (int*)(spart + spart_f);

        // zero forces region of d_out (accumulated across chunk accum passes)
        zero_f32_kernel<<<(n3 + BLK - 1) / BLK, BLK, 0, stream>>>(forces, n3);

        const int CH = (E + nchunks - 1) / nchunks;
        int row0 = 0;
        for (int s = 0; s < E; s += CH) {
            const int ce = min(CH, E - s);
            const int nb = (ce + EPB - 1) / EPB;

            zero_f32_kernel<<<(B + BLK - 1) / BLK, BLK, 0, stream>>>(
                (float*)cnt, B);

            scatter_kernel<<<nb, BLK, 0, stream>>>(
                dEdRij, Rij, idx_i, idx_j, idx_m,
                rec, cnt, spart, s, ce, B, CAP, row0);

            accum_kernel<<<B, BLK, 0, stream>>>(rec, cnt, forces, CAP, n3);

            row0 += nb;
        }

        reduce_stress_kernel<<<(STRESS_FLOATS + BLK - 1) / BLK, BLK, 0, stream>>>(
            spart, cell, stress_out, row0);
    } else {
        // fallback: measured f64 atomic path
        double* facc  = (double*)d_ws;
        float*  spartf = (float*)(facc + n3);

        zero_f64_kernel<<<(n3 + BLK - 1) / BLK, BLK, 0, stream>>>(facc, n3);
        edge_kernel_f64<<<2048, BLK, 0, stream>>>(
            dEdRij, Rij, idx_i, idx_j, idx_m, facc, spartf, E);
        reduce_forces_f64_kernel<<<(n3 + BLK - 1) / BLK, BLK, 0, stream>>>(
            facc, forces, n3);
        reduce_stress_kernel<<<(STRESS_FLOATS + BLK - 1) / BLK, BLK, 0, stream>>>(
            spartf, cell, stress_out, 2048);
    }
}

// Round 10
// 1174.839 us; speedup vs baseline: 2.6262x; 1.4598x over previous
//
#include <hip/hip_runtime.h>
#include <hip/hip_bf16.h>

#define N_MOL 128
#define STRESS_FLOATS (N_MOL * 9)   // 1152
#define APB 400                     // atoms per bucket
#define MAXB 512                    // LDS sizing bound for bucket arrays
#define EPB 2048                    // edges per scatter block (245 blocks @ nc=20)
#define BLK 256

// ---------------------------------------------------------------------------
__global__ void zero_f32_kernel(float* __restrict__ p, size_t n) {
    size_t i = (size_t)blockIdx.x * blockDim.x + threadIdx.x;
    if (i < n) p[i] = 0.f;
}

// ---------------------------------------------------------------------------
// Pass C: per-block histogram -> slot reservation -> record scatter + stress.
// Records: float4(atom_id_bits, fx, fy, fz).
// spart row = blockIdx, ACCUMULATED (+=) across chunk launches (stream-serial,
// exclusive row within a launch -> no race). cnt is per-chunk: cnt[chunk][B],
// pre-zeroed once.
// ---------------------------------------------------------------------------
__global__ void __launch_bounds__(256)
scatter_kernel(const float* __restrict__ dEdRij,
               const float* __restrict__ Rij,
               const int*   __restrict__ idx_i,
               const int*   __restrict__ idx_j,
               const int*   __restrict__ idx_m,
               float4* __restrict__ rec,    // [B][CAP]
               int*    __restrict__ cnt,    // [B] (this chunk's slice)
               float*  __restrict__ spart,  // [rows][1152], RMW across chunks
               int e0_chunk, int n_edges_chunk, int B, int CAP)
{
    __shared__ int   hist[MAXB];
    __shared__ int   base[MAXB];
    __shared__ float smem[STRESS_FLOATS];

    for (int t = threadIdx.x; t < MAXB; t += blockDim.x) hist[t] = 0;
    for (int t = threadIdx.x; t < STRESS_FLOATS; t += blockDim.x) smem[t] = 0.f;
    __syncthreads();

    const int be0 = e0_chunk + blockIdx.x * EPB;
    const int be1 = min(be0 + EPB, e0_chunk + n_edges_chunk);

    // phase 1: bucket histogram
    for (int e = be0 + threadIdx.x; e < be1; e += blockDim.x) {
        atomicAdd(&hist[idx_i[e] / APB], 1);
        atomicAdd(&hist[idx_j[e] / APB], 1);
    }
    __syncthreads();

    // reservation: one global atomic per non-empty (block,bucket)
    for (int t = threadIdx.x; t < B; t += blockDim.x) {
        int h = hist[t];
        base[t] = h ? atomicAdd(&cnt[t], h) : 0;
        hist[t] = 0;                       // reuse as local cursor
    }
    __syncthreads();

    // phase 2: write records + stress LDS accumulation
    for (int e = be0 + threadIdx.x; e < be1; e += blockDim.x) {
        const int i = idx_i[e];
        const int j = idx_j[e];
        const float dx = dEdRij[3*e+0], dy = dEdRij[3*e+1], dz = dEdRij[3*e+2];
        const float rx = Rij[3*e+0],    ry = Rij[3*e+1],    rz = Rij[3*e+2];

        const int m = idx_m[i];
        float* s = &smem[m * 9];
        atomicAdd(&s[0], rx * dx);
        atomicAdd(&s[1], rx * dy);
        atomicAdd(&s[2], rx * dz);
        atomicAdd(&s[3], ry * dx);
        atomicAdd(&s[4], ry * dy);
        atomicAdd(&s[5], ry * dz);
        atomicAdd(&s[6], rz * dx);
        atomicAdd(&s[7], rz * dy);
        atomicAdd(&s[8], rz * dz);

        int bi = i / APB;
        int pos = atomicAdd(&hist[bi], 1);          // LDS cursor
        int slot = base[bi] + pos;
        if (slot < CAP)
            rec[(size_t)bi * CAP + slot] =
                make_float4(__int_as_float(i), dx, dy, dz);

        int bj = j / APB;
        pos  = atomicAdd(&hist[bj], 1);
        slot = base[bj] + pos;
        if (slot < CAP)
            rec[(size_t)bj * CAP + slot] =
                make_float4(__int_as_float(j), -dx, -dy, -dz);
    }

    __syncthreads();
    // accumulate stress partial into this block-slot's row (coalesced RMW)
    float* sp = spart + (size_t)blockIdx.x * STRESS_FLOATS;
    for (int t = threadIdx.x; t < STRESS_FLOATS; t += blockDim.x)
        sp[t] += smem[t];
}

// ---------------------------------------------------------------------------
// Pass D: one block per bucket. Coalesced record read -> LDS accumulate ->
// non-atomic add into forces (exclusive atom ownership per block).
// ---------------------------------------------------------------------------
__global__ void __launch_bounds__(256)
accum_kernel(const float4* __restrict__ rec,
             const int*    __restrict__ cnt,
             float* __restrict__ forces,
             int CAP, int n3)
{
    __shared__ float facc[APB * 3];
    const int b = blockIdx.x;
    for (int t = threadIdx.x; t < APB * 3; t += blockDim.x) facc[t] = 0.f;
    __syncthreads();

    int n = cnt[b];
    if (n > CAP) n = CAP;
    const float4* rb = rec + (size_t)b * CAP;

    for (int r = threadIdx.x; r < n; r += blockDim.x) {
        float4 q = rb[r];
        int a = __float_as_int(q.x);
        int l = a - b * APB;
        atomicAdd(&facc[l * 3 + 0], q.y);
        atomicAdd(&facc[l * 3 + 1], q.z);
        atomicAdd(&facc[l * 3 + 2], q.w);
    }
    __syncthreads();

    const int o = b * APB * 3;
    for (int t = threadIdx.x; t < APB * 3; t += blockDim.x) {
        int a3 = o + t;
        if (a3 < n3) forces[a3] += facc[t];
    }
}

// ---------------------------------------------------------------------------
// stress partials [rows][1152] -> d_out [1152], divided by cell volume.
// rows <= ~1000, data is 1-4.5 MB (L2/L3-resident). 1152 threads, unrolled.
// ---------------------------------------------------------------------------
__global__ void reduce_stress_kernel(const float* __restrict__ spart,
                                     const float* __restrict__ cell,
                                     float* __restrict__ out_stress,
                                     int rows)
{
    int t = blockIdx.x * blockDim.x + threadIdx.x;
    if (t >= STRESS_FLOATS) return;
    float acc = 0.f;
    #pragma unroll 8
    for (int b = 0; b < rows; ++b)
        acc += spart[(size_t)b * STRESS_FLOATS + t];
    const int m = t / 9;
    const float* c = &cell[m * 9];
    const float a0 = c[0], a1 = c[1], a2 = c[2];
    const float b0 = c[3], b1 = c[4], b2 = c[5];
    const float c0 = c[6], c1 = c[7], c2 = c[8];
    const float x0 = b1 * c2 - b2 * c1;
    const float x1 = b2 * c0 - b0 * c2;
    const float x2 = b0 * c1 - b1 * c0;
    const float vol = a0 * x0 + a1 * x1 + a2 * x2;
    out_stress[t] = acc / vol;
}

// ===========================================================================
// Fallback: round-6 measured f64 atomic path (2595 us, known passing)
// ===========================================================================
__global__ void zero_f64_kernel(double* __restrict__ p, int n) {
    int i = blockIdx.x * blockDim.x + threadIdx.x;
    if (i < n) p[i] = 0.0;
}

__global__ void __launch_bounds__(256)
edge_kernel_f64(const float* __restrict__ dEdRij,
                const float* __restrict__ Rij,
                const int*   __restrict__ idx_i,
                const int*   __restrict__ idx_j,
                const int*   __restrict__ idx_m,
                double* __restrict__ facc,
                float*  __restrict__ spart,
                int E)
{
    __shared__ float smem[STRESS_FLOATS];
    for (int t = threadIdx.x; t < STRESS_FLOATS; t += blockDim.x) smem[t] = 0.f;
    __syncthreads();
    const int stride = gridDim.x * blockDim.x;
    for (int e = blockIdx.x * blockDim.x + threadIdx.x; e < E; e += stride) {
        const int i = idx_i[e], j = idx_j[e];
        const float dx = dEdRij[3*e+0], dy = dEdRij[3*e+1], dz = dEdRij[3*e+2];
        const float rx = Rij[3*e+0],    ry = Rij[3*e+1],    rz = Rij[3*e+2];
        double* fi = facc + 3 * (size_t)i;
        unsafeAtomicAdd(fi + 0, (double) dx);
        unsafeAtomicAdd(fi + 1, (double) dy);
        unsafeAtomicAdd(fi + 2, (double) dz);
        double* fj = facc + 3 * (size_t)j;
        unsafeAtomicAdd(fj + 0, (double)-dx);
        unsafeAtomicAdd(fj + 1, (double)-dy);
        unsafeAtomicAdd(fj + 2, (double)-dz);
        const int m = idx_m[i];
        float* s = &smem[m * 9];
        atomicAdd(&s[0], rx*dx); atomicAdd(&s[1], rx*dy); atomicAdd(&s[2], rx*dz);
        atomicAdd(&s[3], ry*dx); atomicAdd(&s[4], ry*dy); atomicAdd(&s[5], ry*dz);
        atomicAdd(&s[6], rz*dx); atomicAdd(&s[7], rz*dy); atomicAdd(&s[8], rz*dz);
    }
    __syncthreads();
    float* sp = spart + (size_t)blockIdx.x * STRESS_FLOATS;
    for (int t = threadIdx.x; t < STRESS_FLOATS; t += blockDim.x) sp[t] = smem[t];
}

__global__ void reduce_forces_f64_kernel(const double* __restrict__ facc,
                                         float* __restrict__ forces, int n3)
{
    int t = blockIdx.x * blockDim.x + threadIdx.x;
    if (t < n3) forces[t] = (float)facc[t];
}

__global__ void reduce_stress_rows_kernel(const float* __restrict__ spart,
                                          const float* __restrict__ cell,
                                          float* __restrict__ out_stress,
                                          int rows)
{
    int t = blockIdx.x * blockDim.x + threadIdx.x;
    if (t >= STRESS_FLOATS) return;
    float acc = 0.f;
    for (int b = 0; b < rows; ++b)
        acc += spart[(size_t)b * STRESS_FLOATS + t];
    const int m = t / 9;
    const float* c = &cell[m * 9];
    const float a0 = c[0], a1 = c[1], a2 = c[2];
    const float b0 = c[3], b1 = c[4], b2 = c[5];
    const float c0 = c[6], c1 = c[7], c2 = c[8];
    const float x0 = b1*c2 - b2*c1, x1 = b2*c0 - b0*c2, x2 = b0*c1 - b1*c0;
    const float vol = a0*x0 + a1*x1 + a2*x2;
    out_stress[t] = acc / vol;
}

// ===========================================================================
extern "C" void kernel_launch(void* const* d_in, const int* in_sizes, int n_in,
                              void* d_out, int out_size, void* d_ws, size_t ws_size,
                              hipStream_t stream)
{
    const float* dEdRij = (const float*)d_in[0];
    const float* Rij    = (const float*)d_in[1];
    const float* R      = (const float*)d_in[2];  (void)R;
    const float* cell   = (const float*)d_in[3];
    const int*   idx_i  = (const int*)d_in[4];
    const int*   idx_j  = (const int*)d_in[5];
    const int*   idx_m  = (const int*)d_in[6];

    const int E  = in_sizes[0] / 3;   // 10,000,000
    const int N  = in_sizes[2] / 3;   // 200,000
    const int n3 = N * 3;

    float* out        = (float*)d_out;
    float* forces     = out;
    float* stress_out = out + (size_t)n3;

    const int B = (N + APB - 1) / APB;   // 500

    // ---- choose fewest chunks that fit:
    //      rec[B][CAP] + spart[rows][1152] + cnt[nchunks][B]
    int nchunks = 0, CAP = 0, ROWS = 0;
    size_t rec_f4 = 0, spart_f = 0;
    if (B <= MAXB) {
        const int cand[9] = {5, 8, 10, 12, 15, 20, 25, 30, 40};
        for (int ci = 0; ci < 9; ++ci) {
            int nc   = cand[ci];
            int CH   = (E + nc - 1) / nc;
            int cap  = (3 * CH) / B + 64;        // 1.5x mean headroom
            int rows = (CH + EPB - 1) / EPB;
            size_t need = (size_t)B * cap * sizeof(float4)
                        + (size_t)rows * STRESS_FLOATS * sizeof(float)
                        + (size_t)nc * B * sizeof(int) + 256;
            if (need <= ws_size) {
                nchunks = nc; CAP = cap; ROWS = rows;
                rec_f4  = (size_t)B * cap;
                spart_f = (size_t)rows * STRESS_FLOATS;
                break;
            }
        }
    }

    if (nchunks > 0) {
        float4* rec   = (float4*)d_ws;
        float*  spart = (float*)(rec + rec_f4);
        int*    cnt   = (int*)(spart + spart_f);   // [nchunks][B]

        // zero spart + all cnt slices in ONE launch (contiguous 4B words)
        const size_t zf = spart_f + (size_t)nchunks * B;
        zero_f32_kernel<<<(int)((zf + BLK - 1) / BLK), BLK, 0, stream>>>(
            spart, zf);
        // zero forces region of d_out (accumulated by accum passes)
        zero_f32_kernel<<<(n3 + BLK - 1) / BLK, BLK, 0, stream>>>(
            forces, (size_t)n3);

        const int CH = (E + nchunks - 1) / nchunks;
        int chunk = 0;
        for (int s = 0; s < E; s += CH, ++chunk) {
            const int ce = min(CH, E - s);
            const int nb = (ce + EPB - 1) / EPB;

            scatter_kernel<<<nb, BLK, 0, stream>>>(
                dEdRij, Rij, idx_i, idx_j, idx_m,
                rec, cnt + (size_t)chunk * B, spart, s, ce, B, CAP);

            accum_kernel<<<B, BLK, 0, stream>>>(
                rec, cnt + (size_t)chunk * B, forces, CAP, n3);
        }

        reduce_stress_kernel<<<(STRESS_FLOATS + BLK - 1) / BLK, BLK, 0, stream>>>(
            spart, cell, stress_out, ROWS);
    } else {
        // fallback: measured f64 atomic path
        double* facc   = (double*)d_ws;
        float*  spartf = (float*)(facc + n3);

        zero_f64_kernel<<<(n3 + BLK - 1) / BLK, BLK, 0, stream>>>(facc, n3);
        edge_kernel_f64<<<2048, BLK, 0, stream>>>(
            dEdRij, Rij, idx_i, idx_j, idx_m, facc, spartf, E);
        reduce_forces_f64_kernel<<<(n3 + BLK - 1) / BLK, BLK, 0, stream>>>(
            facc, forces, n3);
        reduce_stress_rows_kernel<<<(STRESS_FLOATS + BLK - 1) / BLK, BLK, 0, stream>>>(
            spartf, cell, stress_out, 2048);
    }
}